// Round 9
// baseline (104.122 us; speedup 1.0000x reference)
//
#include <hip/hip_runtime.h>
#include <math.h>

#define B 4
#define S 4096
#define N 4096
#define BLK 256
#define SPT 2             // grid points per thread (R4's proven best)
#define NCHUNK 32
#define CSIZE 128         // N / NCHUNK, staged in one LDS pass
#define NT 8              // s-tiles: S / (BLK*SPT)
#define INF 3.4e38f

// Fused kernel: per block (stile, chunk, b) compute partial mins exactly as
// R4; then two-level last-block reduction (group = (b,stile) over 32 chunks;
// final over 32 groups) entirely in-kernel. Counters zeroed by a 256 B
// memset node each replay; reduction order is fixed -> bit-deterministic.
__global__ __launch_bounds__(BLK) void sdf_fused(
    const float* __restrict__ grid,   // [B,S,3]
    const float* __restrict__ gts,    // [B,N,3]
    const float* __restrict__ preds,  // [B,N,3]
    float* __restrict__ partial,      // [2][NCHUNK][B][S]
    unsigned* __restrict__ cnt,       // [NT*B + 1] zeroed each call
    float* __restrict__ pb,           // [NT*B]
    float* __restrict__ out)          // [B]
{
    __shared__ float4 rawp4[CSIZE * 3 / 4];   // 96 float4
    __shared__ float4 rawg4[CSIZE * 3 / 4];
    __shared__ float4 lp[CSIZE];
    __shared__ float4 lg[CSIZE];

    const int tid   = threadIdx.x;
    const int stile = blockIdx.x;            // 8 tiles of 512 s
    const int chunk = blockIdx.y;            // 32 chunks of 128 pts
    const int b     = blockIdx.z;

    const int s0 = stile * (BLK * SPT) + tid;   // gp i at s0 + i*BLK

    float x0[SPT], x1[SPT], x2[SPT], hx[SPT];
    #pragma unroll
    for (int i = 0; i < SPT; ++i) {
        const float* xp = grid + ((size_t)b * S + s0 + i * BLK) * 3;
        x0[i] = -xp[0]; x1[i] = -xp[1]; x2[i] = -xp[2];
        hx[i] = 0.5f * (x0[i] * x0[i] + x1[i] * x1[i] + x2[i] * x2[i]);
    }

    // stage raw chunk (128 pts * 3 floats = 96 float4 per cloud)
    {
        const int n0 = chunk * CSIZE;
        const float4* pv = (const float4*)(preds + ((size_t)b * N + n0) * 3);
        const float4* gv = (const float4*)(gts   + ((size_t)b * N + n0) * 3);
        if (tid < CSIZE * 3 / 4)
            rawp4[tid] = pv[tid];
        else if (tid < CSIZE * 3 / 2)
            rawg4[tid - CSIZE * 3 / 4] = gv[tid - CSIZE * 3 / 4];
    }
    __syncthreads();
    // pack with hy (3-stride LDS reads: 3 coprime 32 -> conflict-free)
    if (tid < CSIZE) {
        const float* rp = (const float*)rawp4;
        float a = rp[3 * tid], c1 = rp[3 * tid + 1], c2 = rp[3 * tid + 2];
        lp[tid] = make_float4(a, c1, c2, 0.5f * (a * a + c1 * c1 + c2 * c2));
    } else {
        const int j = tid - CSIZE;
        const float* rg = (const float*)rawg4;
        float a = rg[3 * j], c1 = rg[3 * j + 1], c2 = rg[3 * j + 2];
        lg[j] = make_float4(a, c1, c2, 0.5f * (a * a + c1 * c1 + c2 * c2));
    }
    __syncthreads();

    float accp[SPT], accg[SPT];
    #pragma unroll
    for (int i = 0; i < SPT; ++i) { accp[i] = INF; accg[i] = INF; }

    #pragma unroll 2
    for (int j = 0; j < CSIZE; j += 4) {
        const float4 p0 = lp[j], p1 = lp[j + 1], p2 = lp[j + 2], p3 = lp[j + 3];
        #pragma unroll
        for (int i = 0; i < SPT; ++i) {
            float a0 = fmaf(x0[i], p0.x, fmaf(x1[i], p0.y, fmaf(x2[i], p0.z, p0.w)));
            float a1 = fmaf(x0[i], p1.x, fmaf(x1[i], p1.y, fmaf(x2[i], p1.z, p1.w)));
            float a2 = fmaf(x0[i], p2.x, fmaf(x1[i], p2.y, fmaf(x2[i], p2.z, p2.w)));
            float a3 = fmaf(x0[i], p3.x, fmaf(x1[i], p3.y, fmaf(x2[i], p3.z, p3.w)));
            accp[i] = fminf(fminf(accp[i], fminf(a0, a1)), fminf(a2, a3));
        }
        const float4 g0 = lg[j], g1 = lg[j + 1], g2 = lg[j + 2], g3 = lg[j + 3];
        #pragma unroll
        for (int i = 0; i < SPT; ++i) {
            float a0 = fmaf(x0[i], g0.x, fmaf(x1[i], g0.y, fmaf(x2[i], g0.z, g0.w)));
            float a1 = fmaf(x0[i], g1.x, fmaf(x1[i], g1.y, fmaf(x2[i], g1.z, g1.w)));
            float a2 = fmaf(x0[i], g2.x, fmaf(x1[i], g2.y, fmaf(x2[i], g2.z, g2.w)));
            float a3 = fmaf(x0[i], g3.x, fmaf(x1[i], g3.y, fmaf(x2[i], g3.z, g3.w)));
            accg[i] = fminf(fminf(accg[i], fminf(a0, a1)), fminf(a2, a3));
        }
    }

    const size_t bs = (size_t)B * S;
    #pragma unroll
    for (int i = 0; i < SPT; ++i) {
        const size_t base = (size_t)b * S + s0 + i * BLK;
        partial[(size_t)chunk * bs + base] = hx[i] + accp[i];
        partial[(size_t)(NCHUNK + chunk) * bs + base] = hx[i] + accg[i];
    }

    // ---- level 1: last block of group (b, stile) reduces its 512 s-values ----
    __threadfence();   // release partials (device scope)
    __shared__ unsigned lastv;
    if (tid == 0) lastv = atomicAdd(&cnt[b * NT + stile], 1u);
    __syncthreads();
    if (lastv != NCHUNK - 1) return;
    __threadfence();   // acquire all groups' partials

    const int sbase = stile * (BLK * SPT);
    float vsum = 0.f;
    #pragma unroll
    for (int i = 0; i < SPT; ++i) {
        const size_t base = (size_t)b * S + sbase + i * BLK + tid;
        float mp = INF, mg = INF;
        #pragma unroll 8
        for (int c = 0; c < NCHUNK; ++c) {
            mp = fminf(mp, partial[(size_t)c * bs + base]);
            mg = fminf(mg, partial[(size_t)(NCHUNK + c) * bs + base]);
        }
        vsum += fabsf(sqrtf(fmaxf(2.f * mp, 0.f)) - sqrtf(fmaxf(2.f * mg, 0.f)));
    }

    #pragma unroll
    for (int off = 32; off > 0; off >>= 1)
        vsum += __shfl_down(vsum, off, 64);

    __shared__ float wsum[BLK / 64];
    if ((tid & 63) == 0) wsum[tid >> 6] = vsum;
    __syncthreads();
    if (tid != 0) return;

    float t = 0.f;
    #pragma unroll
    for (int w = 0; w < BLK / 64; ++w) t += wsum[w];
    pb[b * NT + stile] = t;

    // ---- level 2: last group writes out ----
    __threadfence();
    const unsigned o2 = atomicAdd(&cnt[B * NT], 1u);
    if (o2 == B * NT - 1) {
        __threadfence();
        #pragma unroll
        for (int bb = 0; bb < B; ++bb) {
            float tt = 0.f;
            #pragma unroll
            for (int g = 0; g < NT; ++g) tt += pb[bb * NT + g];
            out[bb] = tt / (float)S;
        }
    }
}

extern "C" void kernel_launch(void* const* d_in, const int* in_sizes, int n_in,
                              void* d_out, int out_size, void* d_ws, size_t ws_size,
                              hipStream_t stream) {
    const float* grid  = (const float*)d_in[0];
    const float* gts   = (const float*)d_in[1];
    const float* preds = (const float*)d_in[2];
    float* out = (float*)d_out;

    // ws layout: partial fp32 8 MB @0 | cnt (33 u32) @64MB | pb (32 f32) @64MB+512
    float*    partial = (float*)d_ws;
    unsigned* cnt     = (unsigned*)((char*)d_ws + (64u << 20));
    float*    pb      = (float*)((char*)d_ws + (64u << 20) + 512);

    hipMemsetAsync(cnt, 0, 256, stream);   // zero counters every call (graph node)

    dim3 g1(NT, NCHUNK, B);                // (8, 32, 4) = 1024 blocks
    sdf_fused<<<g1, BLK, 0, stream>>>(grid, gts, preds, partial, cnt, pb, out);
}

// Round 10
// 20.990 us; speedup vs baseline: 4.9604x; 4.9604x over previous
//
#include <hip/hip_runtime.h>
#include <math.h>

#define B 4
#define S 4096
#define N 4096
#define BLK 256
#define NCHUNK 16
#define CSIZE 256            // N / NCHUNK, cloud points per block per cloud
#define NTILE (CSIZE / 16)   // 16 j-tiles per block
#define W 4                  // s-tiles (of 16 cols) per wave
#define INF 3.4e38f

typedef _Float16 f16x8 __attribute__((ext_vector_type(8)));
typedef float    f32x4 __attribute__((ext_vector_type(4)));

// K-packed Gram MFMA kernel.
// A (cloud, 16 rows=j, K slots 0..4) = {-y0,-y1,-y2, hy_hi, hy_lo}
// B (grid, 16 cols=s, K slots 0..4) = { x0, x1, x2, 1,     1    }
// D[j][s] = hy - x.y = t ; u = hx + min_j t = 0.5*d^2.
// hx, hy computed in fp32 FROM the fp16-quantized coords, so u is exact
// (fp32-level) for the perturbed points -> error ~ |dx|+|dy| ~ 1.7e-3 in d.
__global__ __launch_bounds__(BLK) void sdf_mfma(
    const float* __restrict__ grid,   // [B,S,3]
    const float* __restrict__ gts,    // [B,N,3]
    const float* __restrict__ preds,  // [B,N,3]
    float* __restrict__ partial)      // [2][NCHUNK][B][S]
{
    __shared__ float4 Ap[CSIZE];      // 4 KB: per-point 16B A-frag (preds)
    __shared__ float4 Ag[CSIZE];      // 4 KB: (gts)
    __shared__ float4 Zb;             // 16B zero block for lanes >= 16

    const int tid   = threadIdx.x;
    const int lane  = tid & 63;
    const int wv    = tid >> 6;        // wave 0..3
    const int stile = blockIdx.x;      // 16 tiles of 256 s
    const int chunk = blockIdx.y;      // 16 chunks of 256 cloud pts
    const int b     = blockIdx.z;

    // ---- pack A-frags: thread t packs cloud point t of each cloud ----
    {
        const int n0 = chunk * CSIZE + tid;
        const float* yp = preds + ((size_t)b * N + n0) * 3;
        float y0 = (float)(_Float16)yp[0];
        float y1 = (float)(_Float16)yp[1];
        float y2 = (float)(_Float16)yp[2];
        float hy = 0.5f * (y0 * y0 + y1 * y1 + y2 * y2);
        _Float16 hh = (_Float16)hy;
        _Float16 hl = (_Float16)(hy - (float)hh);
        f16x8 a = { (_Float16)(-y0), (_Float16)(-y1), (_Float16)(-y2),
                    hh, hl, (_Float16)0.f, (_Float16)0.f, (_Float16)0.f };
        *(f16x8*)&Ap[tid] = a;

        const float* gp = gts + ((size_t)b * N + n0) * 3;
        y0 = (float)(_Float16)gp[0];
        y1 = (float)(_Float16)gp[1];
        y2 = (float)(_Float16)gp[2];
        hy = 0.5f * (y0 * y0 + y1 * y1 + y2 * y2);
        hh = (_Float16)hy;
        hl = (_Float16)(hy - (float)hh);
        f16x8 g = { (_Float16)(-y0), (_Float16)(-y1), (_Float16)(-y2),
                    hh, hl, (_Float16)0.f, (_Float16)0.f, (_Float16)0.f };
        *(f16x8*)&Ag[tid] = g;

        if (tid == 0) Zb = make_float4(0.f, 0.f, 0.f, 0.f);
    }

    // ---- B-frags (once per wave): lanes 0-15 carry K-slots 0..7 ----
    const bool lo = (lane < 16);
    const int scol = stile * 256 + wv * 64;   // wave covers s = scol .. scol+63
    f16x8 bf[W];
    float hx[W];
    #pragma unroll
    for (int w = 0; w < W; ++w) {
        const float* xp = grid + ((size_t)b * S + scol + w * 16 + (lane & 15)) * 3;
        float x0 = (float)(_Float16)xp[0];
        float x1 = (float)(_Float16)xp[1];
        float x2 = (float)(_Float16)xp[2];
        hx[w] = 0.5f * (x0 * x0 + x1 * x1 + x2 * x2);
        f16x8 bb = { (_Float16)x0, (_Float16)x1, (_Float16)x2,
                     (_Float16)1.f, (_Float16)1.f,
                     (_Float16)0.f, (_Float16)0.f, (_Float16)0.f };
        if (!lo) {
            f16x8 z = { (_Float16)0.f, (_Float16)0.f, (_Float16)0.f, (_Float16)0.f,
                        (_Float16)0.f, (_Float16)0.f, (_Float16)0.f, (_Float16)0.f };
            bb = z;
        }
        bf[w] = bb;
    }

    __syncthreads();

    // per-lane A read pointers: lanes 0-15 walk the tile, others read zeros
    const char* app = lo ? (const char*)Ap + lane * 16 : (const char*)&Zb;
    const char* agp = lo ? (const char*)Ag + lane * 16 : (const char*)&Zb;
    const int astep = lo ? 256 : 0;   // bytes per j-tile

    const f32x4 zc = { 0.f, 0.f, 0.f, 0.f };
    float accp[W], accg[W];
    #pragma unroll
    for (int w = 0; w < W; ++w) { accp[w] = INF; accg[w] = INF; }

    #pragma unroll 4
    for (int t = 0; t < NTILE; ++t) {
        const f16x8 afp = *(const f16x8*)app;  app += astep;
        const f16x8 afg = *(const f16x8*)agp;  agp += astep;
        #pragma unroll
        for (int w = 0; w < W; ++w) {
            f32x4 d = __builtin_amdgcn_mfma_f32_16x16x32_f16(afp, bf[w], zc, 0, 0, 0);
            accp[w] = fminf(accp[w],
                            fminf(fminf(d[0], d[1]), fminf(d[2], d[3])));
        }
        #pragma unroll
        for (int w = 0; w < W; ++w) {
            f32x4 d = __builtin_amdgcn_mfma_f32_16x16x32_f16(afg, bf[w], zc, 0, 0, 0);
            accg[w] = fminf(accg[w],
                            fminf(fminf(d[0], d[1]), fminf(d[2], d[3])));
        }
    }

    // ---- finish: min across the 4 row-groups (lanes xor 16, 32), store ----
    const size_t bs = (size_t)B * S;
    #pragma unroll
    for (int w = 0; w < W; ++w) {
        float mp = accp[w];
        mp = fminf(mp, __shfl_xor(mp, 16, 64));
        mp = fminf(mp, __shfl_xor(mp, 32, 64));
        float mg = accg[w];
        mg = fminf(mg, __shfl_xor(mg, 16, 64));
        mg = fminf(mg, __shfl_xor(mg, 32, 64));
        if (lo) {
            const size_t sidx = (size_t)b * S + scol + w * 16 + lane;
            const size_t cidx = (size_t)chunk * bs + sidx;
            partial[cidx] = hx[w] + mp;
            partial[(size_t)NCHUNK * bs + cidx] = hx[w] + mg;
        }
    }
}

// Kernel 2: per (tile,b): min over 16 chunks, d = sqrt(max(2u,0)), |diff|,
// block-sum -> pb[b*16 + tile].
__global__ __launch_bounds__(BLK) void sdf_reduce(
    const float* __restrict__ partial, float* __restrict__ pb)
{
    const int tile = blockIdx.x;
    const int b    = blockIdx.y;
    const int tid  = threadIdx.x;
    const int s    = tile * BLK + tid;

    const size_t bs = (size_t)B * S;
    const size_t base = (size_t)b * S + s;

    float mp = INF, mg = INF;
    #pragma unroll
    for (int c = 0; c < NCHUNK; ++c) {
        mp = fminf(mp, partial[(size_t)c * bs + base]);
        mg = fminf(mg, partial[(size_t)(NCHUNK + c) * bs + base]);
    }

    float v = fabsf(sqrtf(fmaxf(2.f * mp, 0.f)) - sqrtf(fmaxf(2.f * mg, 0.f)));

    #pragma unroll
    for (int off = 32; off > 0; off >>= 1)
        v += __shfl_down(v, off, 64);

    __shared__ float wsum[BLK / 64];
    if ((tid & 63) == 0) wsum[tid >> 6] = v;
    __syncthreads();
    if (tid == 0) {
        float t = 0.f;
        #pragma unroll
        for (int w = 0; w < BLK / 64; ++w) t += wsum[w];
        pb[b * gridDim.x + tile] = t;
    }
}

// Kernel 3: final tiny reduction (16 tiles x 4 batches).
__global__ __launch_bounds__(64) void sdf_final(
    const float* __restrict__ pb, float* __restrict__ out)
{
    const int tid = threadIdx.x;
    float v = (tid < 64) ? pb[tid] : 0.f;
    #pragma unroll
    for (int off = 8; off > 0; off >>= 1)
        v += __shfl_down(v, off, 16);
    if ((tid & 15) == 0)
        out[tid / 16] = v / (float)S;
}

extern "C" void kernel_launch(void* const* d_in, const int* in_sizes, int n_in,
                              void* d_out, int out_size, void* d_ws, size_t ws_size,
                              hipStream_t stream) {
    const float* grid  = (const float*)d_in[0];
    const float* gts   = (const float*)d_in[1];
    const float* preds = (const float*)d_in[2];
    float* out = (float*)d_out;

    // ws: partial fp32 2 MB @0 | pb (64 f32) @4MB
    float* partial = (float*)d_ws;
    float* pb      = (float*)((char*)d_ws + (4u << 20));

    dim3 g1(S / 256, NCHUNK, B);             // (16, 16, 4) = 1024 blocks
    sdf_mfma<<<g1, BLK, 0, stream>>>(grid, gts, preds, partial);

    dim3 g2(S / BLK, B);                     // (16, 4) = 64 blocks
    sdf_reduce<<<g2, BLK, 0, stream>>>(partial, pb);

    sdf_final<<<1, 64, 0, stream>>>(pb, out);
}

// Round 11
// 17.075 us; speedup vs baseline: 6.0978x; 1.2293x over previous
//
#include <hip/hip_runtime.h>
#include <math.h>

#define B 4
#define S 4096
#define N 4096
#define BLK 512            // 8 waves; block covers 64 s, all of N
#define PASS 1024          // cloud points staged per LDS pass
#define NPASS (N / PASS)   // 4
#define JT 8               // j-tiles per wave per pass (64 tiles / 8 waves)
#define W 4                // s-tiles per wave (64 s)
#define INF 3.4e38f

typedef _Float16 f16x8 __attribute__((ext_vector_type(8)));
typedef float    f32x4 __attribute__((ext_vector_type(4)));

// K-packed Gram MFMA, full-N per block (no global partials).
// A (cloud pt j): {-y0,-y1,-y2, hy_hi, hy_lo, 0,0,0};  B (grid s): {x0,x1,x2,1,1,0,0,0}
// D[j][s] = hy - x.y ; u = hx + min_j D ; d = sqrt(max(2u,0)).
// hx,hy computed in fp32 from fp16-quantized coords (error = point perturbation).
__global__ __launch_bounds__(BLK) void sdf_mfma(
    const float* __restrict__ grid,   // [B,S,3]
    const float* __restrict__ gts,    // [B,N,3]
    const float* __restrict__ preds,  // [B,N,3]
    float* __restrict__ pb)           // [B][S/64] block sums
{
    __shared__ float4 Ap[PASS];       // 16 KB
    __shared__ float4 Ag[PASS];       // 16 KB
    __shared__ float  smin[8][2][64]; // 4 KB cross-wave mins
    __shared__ float4 Zb;             // zero A-frag for lanes >= 16

    const int tid   = threadIdx.x;
    const int lane  = tid & 63;
    const int wv    = tid >> 6;       // 0..7
    const int stile = blockIdx.x;     // 64 tiles of 64 s
    const int b     = blockIdx.y;
    const int scol  = stile * 64;

    // ---- B-frags + hx (per wave, lanes 0-15 active) ----
    const bool lo = (lane < 16);
    f16x8 bf[W];
    float hx[W];
    #pragma unroll
    for (int w = 0; w < W; ++w) {
        const float* xp = grid + ((size_t)b * S + scol + w * 16 + (lane & 15)) * 3;
        float x0 = (float)(_Float16)xp[0];
        float x1 = (float)(_Float16)xp[1];
        float x2 = (float)(_Float16)xp[2];
        hx[w] = 0.5f * (x0 * x0 + x1 * x1 + x2 * x2);
        f16x8 bb = { (_Float16)x0, (_Float16)x1, (_Float16)x2,
                     (_Float16)1.f, (_Float16)1.f,
                     (_Float16)0.f, (_Float16)0.f, (_Float16)0.f };
        if (!lo) {
            f16x8 z = { (_Float16)0.f, (_Float16)0.f, (_Float16)0.f, (_Float16)0.f,
                        (_Float16)0.f, (_Float16)0.f, (_Float16)0.f, (_Float16)0.f };
            bb = z;
        }
        bf[w] = bb;
    }
    if (tid == 0) Zb = make_float4(0.f, 0.f, 0.f, 0.f);

    const f32x4 zc = { 0.f, 0.f, 0.f, 0.f };
    float accp[W], accg[W];
    #pragma unroll
    for (int w = 0; w < W; ++w) { accp[w] = INF; accg[w] = INF; }

    for (int pass = 0; pass < NPASS; ++pass) {
        __syncthreads();   // previous pass fully consumed
        // ---- stage + pack 1024 pts per cloud (2 per thread) ----
        #pragma unroll
        for (int q = 0; q < 2; ++q) {
            const int p = pass * PASS + tid + q * BLK;
            const int d = tid + q * BLK;
            const float* yp = preds + ((size_t)b * N + p) * 3;
            float y0 = (float)(_Float16)yp[0];
            float y1 = (float)(_Float16)yp[1];
            float y2 = (float)(_Float16)yp[2];
            float hy = 0.5f * (y0 * y0 + y1 * y1 + y2 * y2);
            _Float16 hh = (_Float16)hy;
            _Float16 hl = (_Float16)(hy - (float)hh);
            f16x8 a = { (_Float16)(-y0), (_Float16)(-y1), (_Float16)(-y2),
                        hh, hl, (_Float16)0.f, (_Float16)0.f, (_Float16)0.f };
            *(f16x8*)&Ap[d] = a;

            const float* gp = gts + ((size_t)b * N + p) * 3;
            y0 = (float)(_Float16)gp[0];
            y1 = (float)(_Float16)gp[1];
            y2 = (float)(_Float16)gp[2];
            hy = 0.5f * (y0 * y0 + y1 * y1 + y2 * y2);
            hh = (_Float16)hy;
            hl = (_Float16)(hy - (float)hh);
            f16x8 g = { (_Float16)(-y0), (_Float16)(-y1), (_Float16)(-y2),
                        hh, hl, (_Float16)0.f, (_Float16)0.f, (_Float16)0.f };
            *(f16x8*)&Ag[d] = g;
        }
        __syncthreads();

        // ---- wave's slice: j-tiles [wv*JT, wv*JT+JT) of this pass ----
        const char* app = lo ? (const char*)(Ap + (size_t)wv * (JT * 16)) + lane * 16
                             : (const char*)&Zb;
        const char* agp = lo ? (const char*)(Ag + (size_t)wv * (JT * 16)) + lane * 16
                             : (const char*)&Zb;
        const int astep = lo ? 256 : 0;

        #pragma unroll
        for (int g2 = 0; g2 < JT / 4; ++g2) {
            const f16x8 p0 = *(const f16x8*)(app + 0 * astep);
            const f16x8 p1 = *(const f16x8*)(app + 1 * astep);
            const f16x8 p2 = *(const f16x8*)(app + 2 * astep);
            const f16x8 p3 = *(const f16x8*)(app + 3 * astep);
            app += 4 * astep;
            const f16x8 q0 = *(const f16x8*)(agp + 0 * astep);
            const f16x8 q1 = *(const f16x8*)(agp + 1 * astep);
            const f16x8 q2 = *(const f16x8*)(agp + 2 * astep);
            const f16x8 q3 = *(const f16x8*)(agp + 3 * astep);
            agp += 4 * astep;

            #pragma unroll
            for (int w = 0; w < W; ++w) {
                f32x4 dA = __builtin_amdgcn_mfma_f32_16x16x32_f16(p0, bf[w], zc, 0, 0, 0);
                f32x4 dB = __builtin_amdgcn_mfma_f32_16x16x32_f16(p1, bf[w], zc, 0, 0, 0);
                f32x4 dC = __builtin_amdgcn_mfma_f32_16x16x32_f16(p2, bf[w], zc, 0, 0, 0);
                f32x4 dD = __builtin_amdgcn_mfma_f32_16x16x32_f16(p3, bf[w], zc, 0, 0, 0);
                // min3-shaped fold: 8 instr per 4 MFMA
                float u0 = fminf(fminf(dA[0], dB[0]), dC[0]);
                float u1 = fminf(fminf(dA[1], dB[1]), dC[1]);
                float u2 = fminf(fminf(dA[2], dB[2]), dC[2]);
                float u3 = fminf(fminf(dA[3], dB[3]), dC[3]);
                float v0 = fminf(fminf(u0, u1), dD[0]);
                float v1 = fminf(fminf(u2, u3), dD[1]);
                float v2 = fminf(fminf(dD[2], dD[3]), accp[w]);
                accp[w] = fminf(fminf(v0, v1), v2);
            }
            #pragma unroll
            for (int w = 0; w < W; ++w) {
                f32x4 dA = __builtin_amdgcn_mfma_f32_16x16x32_f16(q0, bf[w], zc, 0, 0, 0);
                f32x4 dB = __builtin_amdgcn_mfma_f32_16x16x32_f16(q1, bf[w], zc, 0, 0, 0);
                f32x4 dC = __builtin_amdgcn_mfma_f32_16x16x32_f16(q2, bf[w], zc, 0, 0, 0);
                f32x4 dD = __builtin_amdgcn_mfma_f32_16x16x32_f16(q3, bf[w], zc, 0, 0, 0);
                float u0 = fminf(fminf(dA[0], dB[0]), dC[0]);
                float u1 = fminf(fminf(dA[1], dB[1]), dC[1]);
                float u2 = fminf(fminf(dA[2], dB[2]), dC[2]);
                float u3 = fminf(fminf(dA[3], dB[3]), dC[3]);
                float v0 = fminf(fminf(u0, u1), dD[0]);
                float v1 = fminf(fminf(u2, u3), dD[1]);
                float v2 = fminf(fminf(dD[2], dD[3]), accg[w]);
                accg[w] = fminf(fminf(v0, v1), v2);
            }
        }
    }

    // ---- lane fold (rows) + cross-wave fold + block |diff| sum ----
    #pragma unroll
    for (int w = 0; w < W; ++w) {
        float mp = accp[w];
        mp = fminf(mp, __shfl_xor(mp, 16, 64));
        mp = fminf(mp, __shfl_xor(mp, 32, 64));
        float mg = accg[w];
        mg = fminf(mg, __shfl_xor(mg, 16, 64));
        mg = fminf(mg, __shfl_xor(mg, 32, 64));
        if (lo) {
            smin[wv][0][w * 16 + lane] = hx[w] + mp;
            smin[wv][1][w * 16 + lane] = hx[w] + mg;
        }
    }
    __syncthreads();
    if (tid < 64) {
        float mp = INF, mg = INF;
        #pragma unroll
        for (int v2 = 0; v2 < 8; ++v2) {
            mp = fminf(mp, smin[v2][0][tid]);
            mg = fminf(mg, smin[v2][1][tid]);
        }
        float v = fabsf(sqrtf(fmaxf(2.f * mp, 0.f)) - sqrtf(fmaxf(2.f * mg, 0.f)));
        #pragma unroll
        for (int off = 32; off > 0; off >>= 1)
            v += __shfl_down(v, off, 64);
        if (tid == 0) pb[b * 64 + stile] = v;
    }
}

// Final: 256 threads = 4 waves; wave b reduces its 64 tile-sums -> out[b].
__global__ __launch_bounds__(256) void sdf_final(
    const float* __restrict__ pb, float* __restrict__ out)
{
    const int tid = threadIdx.x;
    float v = pb[tid];
    #pragma unroll
    for (int off = 32; off > 0; off >>= 1)
        v += __shfl_down(v, off, 64);
    if ((tid & 63) == 0) out[tid >> 6] = v / (float)S;
}

extern "C" void kernel_launch(void* const* d_in, const int* in_sizes, int n_in,
                              void* d_out, int out_size, void* d_ws, size_t ws_size,
                              hipStream_t stream) {
    const float* grid  = (const float*)d_in[0];
    const float* gts   = (const float*)d_in[1];
    const float* preds = (const float*)d_in[2];
    float* out = (float*)d_out;
    float* pb  = (float*)d_ws;        // 256 floats

    dim3 g1(S / 64, B);               // (64, 4) = 256 blocks, 1 per CU
    sdf_mfma<<<g1, BLK, 0, stream>>>(grid, gts, preds, pb);

    sdf_final<<<1, 256, 0, stream>>>(pb, out);
}

// Round 12
// 13.162 us; speedup vs baseline: 7.9107x; 1.2973x over previous
//
#include <hip/hip_runtime.h>
#include <math.h>

#define B 4
#define S 4096
#define N 4096
#define BLK 1024           // 16 waves, 1 block/CU (VGPR-limited), 4 waves/SIMD
#define NW 16
#define W 2                // two 32-col B-frags -> 64 s per block
#define PASS 2048          // cloud pts per LDS pass per cloud (32 KB x 2 clouds)
#define NPASS 2
#define JTW 4              // j-tiles (32 rows) per wave per pass = PASS/32/NW
#define INF 3.4e38f

typedef _Float16 f16x8  __attribute__((ext_vector_type(8)));
typedef float    f32x16 __attribute__((ext_vector_type(16)));

// 32x32x16 K-packed Gram MFMA, full-N per block.
// A (cloud pt j, rows=lane&31, k=(lane>>5)*8+idx): {-y0,-y1,-y2,hy_hi,hy_lo,0,0,0}
// B (grid s, cols=lane&31): lanes<32 {x0,x1,x2,1,1,0,0,0}; lanes>=32 ZERO,
// so A's k=8..15 content (garbage/duplicate) contributes A*0 = 0.
// D[j][s] = hy - x.y ; u = hx + min_j D ; d = sqrt(max(2u,0)).
__global__ __launch_bounds__(BLK) void sdf_mfma(
    const float* __restrict__ grid,   // [B,S,3]
    const float* __restrict__ gts,    // [B,N,3]
    const float* __restrict__ preds,  // [B,N,3]
    float* __restrict__ pb)           // [B][S/64]
{
    __shared__ float4 Ap[PASS];       // 32 KB
    __shared__ float4 Ag[PASS];       // 32 KB   (total 64 KB)

    const int tid   = threadIdx.x;
    const int lane  = tid & 63;
    const int wv    = tid >> 6;       // 0..15
    const int l31   = lane & 31;
    const int stile = blockIdx.x;     // 64 tiles of 64 s
    const int b     = blockIdx.y;
    const int scol  = stile * 64;

    // ---- B-frags + hx (cols = lane&31; lanes 32-63 zero => kill k=8..15) ----
    const bool lo32 = (lane < 32);
    f16x8 bf[W];
    float hx[W];
    #pragma unroll
    for (int w = 0; w < W; ++w) {
        const float* xp = grid + ((size_t)b * S + scol + w * 32 + l31) * 3;
        float x0 = (float)(_Float16)xp[0];
        float x1 = (float)(_Float16)xp[1];
        float x2 = (float)(_Float16)xp[2];
        hx[w] = 0.5f * (x0 * x0 + x1 * x1 + x2 * x2);
        f16x8 bb = { (_Float16)x0, (_Float16)x1, (_Float16)x2,
                     (_Float16)1.f, (_Float16)1.f,
                     (_Float16)0.f, (_Float16)0.f, (_Float16)0.f };
        f16x8 z  = { (_Float16)0.f, (_Float16)0.f, (_Float16)0.f, (_Float16)0.f,
                     (_Float16)0.f, (_Float16)0.f, (_Float16)0.f, (_Float16)0.f };
        bf[w] = lo32 ? bb : z;
    }

    float accp[W], accg[W];
    #pragma unroll
    for (int w = 0; w < W; ++w) { accp[w] = INF; accg[w] = INF; }

    for (int p = 0; p < NPASS; ++p) {
        // ---- stage + pack pass p (2 frags per cloud per thread) ----
        #pragma unroll
        for (int q = 0; q < PASS / BLK; ++q) {
            const int n = p * PASS + q * BLK + tid;
            const int d = q * BLK + tid;
            const float* yp = preds + ((size_t)b * N + n) * 3;
            float y0 = (float)(_Float16)yp[0];
            float y1 = (float)(_Float16)yp[1];
            float y2 = (float)(_Float16)yp[2];
            float hy = 0.5f * (y0 * y0 + y1 * y1 + y2 * y2);
            _Float16 hh = (_Float16)hy;
            _Float16 hl = (_Float16)(hy - (float)hh);
            f16x8 a = { (_Float16)(-y0), (_Float16)(-y1), (_Float16)(-y2),
                        hh, hl, (_Float16)0.f, (_Float16)0.f, (_Float16)0.f };
            *(f16x8*)&Ap[d] = a;

            const float* gp = gts + ((size_t)b * N + n) * 3;
            y0 = (float)(_Float16)gp[0];
            y1 = (float)(_Float16)gp[1];
            y2 = (float)(_Float16)gp[2];
            hy = 0.5f * (y0 * y0 + y1 * y1 + y2 * y2);
            hh = (_Float16)hy;
            hl = (_Float16)(hy - (float)hh);
            f16x8 g = { (_Float16)(-y0), (_Float16)(-y1), (_Float16)(-y2),
                        hh, hl, (_Float16)0.f, (_Float16)0.f, (_Float16)0.f };
            *(f16x8*)&Ag[d] = g;
        }
        __syncthreads();

        // ---- compute: wave's JTW j-tiles of 32 rows each ----
        const char* app = (const char*)Ap + ((size_t)wv * JTW * 32 + l31) * 16;
        const char* agp = (const char*)Ag + ((size_t)wv * JTW * 32 + l31) * 16;

        #pragma unroll
        for (int jt = 0; jt < JTW; ++jt) {
            const f16x8 afp = *(const f16x8*)(app + jt * 512);
            const f16x8 afg = *(const f16x8*)(agp + jt * 512);
            const f32x16 zc = { 0.f, 0.f, 0.f, 0.f, 0.f, 0.f, 0.f, 0.f,
                                0.f, 0.f, 0.f, 0.f, 0.f, 0.f, 0.f, 0.f };
            #pragma unroll
            for (int w = 0; w < W; ++w) {
                f32x16 d = __builtin_amdgcn_mfma_f32_32x32x16_f16(afp, bf[w], zc, 0, 0, 0);
                float a = accp[w];
                a = fminf(fminf(a, d[0]),  d[1]);    // v_min3 shapes
                a = fminf(fminf(a, d[2]),  d[3]);
                a = fminf(fminf(a, d[4]),  d[5]);
                a = fminf(fminf(a, d[6]),  d[7]);
                a = fminf(fminf(a, d[8]),  d[9]);
                a = fminf(fminf(a, d[10]), d[11]);
                a = fminf(fminf(a, d[12]), d[13]);
                a = fminf(fminf(a, d[14]), d[15]);
                accp[w] = a;
            }
            #pragma unroll
            for (int w = 0; w < W; ++w) {
                f32x16 d = __builtin_amdgcn_mfma_f32_32x32x16_f16(afg, bf[w], zc, 0, 0, 0);
                float a = accg[w];
                a = fminf(fminf(a, d[0]),  d[1]);
                a = fminf(fminf(a, d[2]),  d[3]);
                a = fminf(fminf(a, d[4]),  d[5]);
                a = fminf(fminf(a, d[6]),  d[7]);
                a = fminf(fminf(a, d[8]),  d[9]);
                a = fminf(fminf(a, d[10]), d[11]);
                a = fminf(fminf(a, d[12]), d[13]);
                a = fminf(fminf(a, d[14]), d[15]);
                accg[w] = a;
            }
        }
        __syncthreads();   // buffer consumed by all waves before re-stage / smin
    }

    // ---- cross-lane (rows split over lane>>5) + cross-wave + block tail ----
    float* sm = (float*)Ap;   // reuse LDS: [NW][2][64] = 8 KB (barrier above)
    #pragma unroll
    for (int w = 0; w < W; ++w) {
        float mp = fminf(accp[w], __shfl_xor(accp[w], 32, 64));
        float mg = fminf(accg[w], __shfl_xor(accg[w], 32, 64));
        if (lo32) {
            sm[(wv * 2 + 0) * 64 + w * 32 + l31] = hx[w] + mp;
            sm[(wv * 2 + 1) * 64 + w * 32 + l31] = hx[w] + mg;
        }
    }
    __syncthreads();
    if (tid < 64) {
        float mp = INF, mg = INF;
        #pragma unroll
        for (int v = 0; v < NW; ++v) {
            mp = fminf(mp, sm[(v * 2 + 0) * 64 + tid]);
            mg = fminf(mg, sm[(v * 2 + 1) * 64 + tid]);
        }
        float v = fabsf(sqrtf(fmaxf(2.f * mp, 0.f)) - sqrtf(fmaxf(2.f * mg, 0.f)));
        #pragma unroll
        for (int off = 32; off > 0; off >>= 1)
            v += __shfl_down(v, off, 64);
        if (tid == 0) pb[b * 64 + stile] = v;
    }
}

// Final: 256 threads = 4 waves; wave b reduces its 64 tile-sums -> out[b].
__global__ __launch_bounds__(256) void sdf_final(
    const float* __restrict__ pb, float* __restrict__ out)
{
    const int tid = threadIdx.x;
    float v = pb[tid];
    #pragma unroll
    for (int off = 32; off > 0; off >>= 1)
        v += __shfl_down(v, off, 64);
    if ((tid & 63) == 0) out[tid >> 6] = v / (float)S;
}

extern "C" void kernel_launch(void* const* d_in, const int* in_sizes, int n_in,
                              void* d_out, int out_size, void* d_ws, size_t ws_size,
                              hipStream_t stream) {
    const float* grid  = (const float*)d_in[0];
    const float* gts   = (const float*)d_in[1];
    const float* preds = (const float*)d_in[2];
    float* out = (float*)d_out;
    float* pb  = (float*)d_ws;        // 256 floats

    dim3 g1(S / 64, B);               // (64, 4) = 256 blocks, 1 per CU
    sdf_mfma<<<g1, BLK, 0, stream>>>(grid, gts, preds, pb);

    sdf_final<<<1, 256, 0, stream>>>(pb, out);
}